// Round 10
// baseline (305.101 us; speedup 1.0000x reference)
//
#include <hip/hip_runtime.h>
#include <hip/hip_bf16.h>
#include <stdint.h>

#define BB 16
#define NZ 2048
#define NE 2048
#define DD 512

typedef unsigned short u16;
typedef __attribute__((ext_vector_type(8))) _Float16 f16x8;  // 8 fp16 = 4 VGPR
typedef __attribute__((ext_vector_type(4))) float f32x4;

// ---------- helpers ----------
__device__ __forceinline__ u16 f2h(float f) {
  _Float16 h = (_Float16)f;                 // v_cvt_f16_f32, RNE
  return __builtin_bit_cast(u16, h);
}

__device__ __forceinline__ float h2f(u16 h) {
  return (float)__builtin_bit_cast(_Float16, h);
}

__device__ __forceinline__ void gload_lds16(const void* g, void* l) {
  auto gp = (const __attribute__((address_space(1))) uint32_t*)g;
  auto lp = (__attribute__((address_space(3))) uint32_t*)l;
  __builtin_amdgcn_global_load_lds(gp, lp, 16, 0, 0);
}

// ---------- f32 -> fp16 bulk convert ----------
__global__ void k_cvt(const float* __restrict__ in, u16* __restrict__ out, int n4) {
  int i = blockIdx.x * blockDim.x + threadIdx.x;
  int stride = gridDim.x * blockDim.x;
  for (; i < n4; i += stride) {
    float4 v = ((const float4*)in)[i];
    ushort4 o;
    o.x = f2h(v.x); o.y = f2h(v.y); o.z = f2h(v.z); o.w = f2h(v.w);
    ((ushort4*)out)[i] = o;
  }
}

// ---------- M[512x512] -> Mt fp16 (Mt[e][d] = M[d][e]) ----------
__global__ void k_mt(const float* __restrict__ M, u16* __restrict__ Mt) {
  __shared__ float t[32][33];
  int bx = blockIdx.x * 32;  // e range
  int by = blockIdx.y * 32;  // d range
  for (int r = 0; r < 32; r += 8)
    t[threadIdx.y + r][threadIdx.x] = M[(size_t)(by + threadIdx.y + r) * DD + bx + threadIdx.x];
  __syncthreads();
  for (int r = 0; r < 32; r += 8)
    Mt[(size_t)(bx + threadIdx.y + r) * DD + by + threadIdx.x] = f2h(t[threadIdx.x][threadIdx.y + r]);
}

// ---------- eT'[b][d][m] = fp16( eH[b][m][d] * 2048 / colsum[b][m] ) ----------
__global__ void k_et(const u16* __restrict__ eH, const float* __restrict__ cs,
                     u16* __restrict__ eT) {
  __shared__ float t[32][33];
  int b = blockIdx.z;
  int m0 = blockIdx.y * 32, d0 = blockIdx.x * 32;
  const u16* eb = eH + (size_t)b * NE * DD;
  const float* csb = cs + (size_t)b * NE;
  for (int r = 0; r < 32; r += 8) {
    int m = m0 + threadIdx.y + r;
    t[threadIdx.y + r][threadIdx.x] =
        h2f(eb[(size_t)m * DD + d0 + threadIdx.x]) * (2048.0f / csb[m]);
  }
  __syncthreads();
  u16* eTb = eT + (size_t)b * DD * NE;
  for (int r = 0; r < 32; r += 8) {
    int d = d0 + threadIdx.y + r;
    eTb[(size_t)d * NE + m0 + threadIdx.x] = f2h(t[threadIdx.x][threadIdx.y + r]);
  }
}

// ---------- 128x128 tile, BK=32, 4-wave fp16 gemm_bt, 3 blocks/CU ----------
// C = A[M x K] * Bt[N x K]^T.  256 threads = 4 waves (2M x 2N), per-wave 64x64.
// LDS 32 KiB dynamic, LINEAR rows of 64 B (32 k-elem), double-buffered:
//   A[buf] @ buf*8192, B[buf] @ 16384 + buf*8192; slot (r, c4) @ r*64 + c4*16.
// XOR chunk swizzle (both-sides, m201 #21): slot (r,c4) holds source chunk
// q = c4 ^ ((r>>1)&3) of row r.  Staging source permutes 16B chunks WITHIN a
// 64B row (coalescing preserved); ds_read applies the same XOR -> 16 row-lanes
// spread over all 32 banks, 2 lanes/bank = free (m136).  Kills r2's 8.4M
// 8-way conflicts while keeping its coalesced staging.
// m97-style K-loop, 1 sync/K-step; compiler's pre-barrier drain is covered by
// ~3 sibling blocks/CU (launch_bounds(256,3); ~136 regs/wave -> 12 waves/CU).
// Epilogue: LDS-staged bank-swizzled C-tile, coalesced dwordx4 writeback (r8).
// EPI: 0 = fp16 out; 1 = exp(sigmoid(x)) fp16 out + colsum atomics; 2 = f32/2048
template<int EPI, int KDIM>
__global__ __launch_bounds__(256, 3) void k_gemm(
    const u16* __restrict__ A, const u16* __restrict__ Bt, void* __restrict__ Cp,
    int Ndim, long long sAb, long long sBb, long long sCb,
    float* __restrict__ colsum, int csld)
{
  extern __shared__ char lds[];
  constexpr int NT = KDIM / 32;

  // bijective XCD-aware swizzle (nwg % 8 == 0 for all our launches)
  const int gx = gridDim.x, gy = gridDim.y;
  const int nwg = gx * gy * gridDim.z;
  const int hid = blockIdx.x + gx * (blockIdx.y + gy * blockIdx.z);
  const int logical = (hid & 7) * (nwg >> 3) + (hid >> 3);
  const int bx = logical % gx;
  const int rem0 = logical / gx;
  const int by = rem0 % gy;
  const int bz = rem0 / gy;

  const int tid = threadIdx.x;
  const int lane = tid & 63;
  const int wid = tid >> 6;
  const int wr = wid >> 1;   // 0..1
  const int wc = wid & 1;    // 0..1

  const int row0 = by * 128;
  const int col0 = bx * 128;

  const u16* Ab = A + (long long)bz * sAb;
  const u16* Bb = Bt + (long long)bz * sBb;

  // staging sources (linear dest, XOR-permuted source chunk within the row):
  // instr c covers LDS slots idx = c*256 + tid;  r = idx>>2, cL = idx&3,
  // source chunk q = cL ^ ((r>>1)&3)  -> still inside row r's 64B (coalesced)
  const u16* srcA[2]; const u16* srcB[2];
#pragma unroll
  for (int c = 0; c < 2; ++c) {
    int idx = c * 256 + tid;
    int r = idx >> 2;
    int cL = idx & 3;
    int q = cL ^ ((r >> 1) & 3);
    srcA[c] = Ab + (long long)(row0 + r) * KDIM + q * 8;
    srcB[c] = Bb + (long long)(col0 + r) * KDIM + q * 8;
  }

  auto stage = [&](char* dA, char* dB, int k0) {
#pragma unroll
    for (int c = 0; c < 2; ++c)
      gload_lds16(srcA[c] + k0, dA + (c * 256 + wid * 64) * 16);
#pragma unroll
    for (int c = 0; c < 2; ++c)
      gload_lds16(srcB[c] + k0, dB + (c * 256 + wid * 64) * 16);
  };

  f32x4 acc[4][4] = {};

  const int p15 = lane & 15;
  const int cswz = (lane >> 4) ^ ((p15 >> 1) & 3);  // read chunk after XOR

  // buffers: A[buf] @ buf*8192, B[buf] @ 16384 + buf*8192
  stage(lds, lds + 16384, 0);
  __syncthreads();

  for (int t = 0; t < NT; ++t) {
    const int buf = t & 1;
    char* lA = lds + buf * 8192;
    char* lB = lds + 16384 + buf * 8192;
    if (t + 1 < NT)
      stage(lds + (buf ^ 1) * 8192, lds + 16384 + (buf ^ 1) * 8192, (t + 1) * 32);

    f16x8 af[4], bf[4];
#pragma unroll
    for (int m = 0; m < 4; ++m) {
      int r = wr * 64 + m * 16 + p15;
      af[m] = *(const f16x8*)(lA + r * 64 + cswz * 16);
    }
#pragma unroll
    for (int n = 0; n < 4; ++n) {
      int r = wc * 64 + n * 16 + p15;
      bf[n] = *(const f16x8*)(lB + r * 64 + cswz * 16);
    }
#pragma unroll
    for (int m = 0; m < 4; ++m)
#pragma unroll
      for (int n = 0; n < 4; ++n)
        acc[m][n] = __builtin_amdgcn_mfma_f32_16x16x32_f16(af[m], bf[n], acc[m][n], 0, 0, 0);

    __syncthreads();   // drains vmcnt+lgkmcnt (compiler); sibling blocks cover
  }

  // C/D frag layout: col = lane&15, row = (lane>>4)*4 + j
  const int rr = (lane >> 4) * 4;
  const int cc = lane & 15;
  const int grow = row0 + wr * 64;
  const int gcol = col0 + wc * 64;

  if constexpr (EPI == 0 || EPI == 1) {
    // stage u16 64x64 wave-tile in LDS (8 KiB/wave), then coalesced dwordx4
    char* wb = lds + wid * 8192;
    float csum[4] = {0.f, 0.f, 0.f, 0.f};
#pragma unroll
    for (int m = 0; m < 4; ++m)
#pragma unroll
      for (int n = 0; n < 4; ++n)
#pragma unroll
        for (int j = 0; j < 4; ++j) {
          float x = acc[m][n][j];
          float v;
          if constexpr (EPI == 1) {
            float s = 1.f / (1.f + __expf(-x));   // sigmoid
            v = __expf(s);                        // in (1, e)
            csum[n] += v;
          } else {
            v = x;
          }
          int rl = m * 16 + rr + j;              // 0..63
          int col = n * 16 + cc;                 // 0..63
          int chunk = (col >> 3) ^ (rl & 7);     // bank swizzle
          *(u16*)(wb + rl * 128 + chunk * 16 + ((col * 2) & 15)) = f2h(v);
        }
    if constexpr (EPI == 1) {
#pragma unroll
      for (int n = 0; n < 4; ++n) {
        float v = csum[n];
        v += __shfl_xor(v, 16, 64);
        v += __shfl_xor(v, 32, 64);
        if ((lane >> 4) == 0)
          atomicAdd(&colsum[(long long)bz * csld + gcol + n * 16 + cc], v);
      }
    }
    __syncthreads();   // cross-lane LDS write->read ordering (r6 fix)
    u16* C = (u16*)Cp + (long long)bz * sCb;
#pragma unroll
    for (int s = 0; s < 8; ++s) {
      int rl = (lane >> 3) + s * 8;
      int chunk = (lane & 7) ^ (rl & 7);
      f16x8 v = *(const f16x8*)(wb + rl * 128 + chunk * 16);
      *(f16x8*)(&C[(long long)(grow + rl) * Ndim + gcol + (lane & 7) * 8]) = v;
    }
  } else {
    // f32 out: two 32-row passes, 8 KiB/wave each, coalesced dwordx4
    float* C = (float*)Cp + (long long)bz * sCb;
    char* wb = lds + wid * 8192;
#pragma unroll
    for (int h = 0; h < 2; ++h) {
      if (h) __syncthreads();                    // pass-0 reads done before overwrite
#pragma unroll
      for (int mm = 0; mm < 2; ++mm) {
        int m = h * 2 + mm;
#pragma unroll
        for (int n = 0; n < 4; ++n)
#pragma unroll
          for (int j = 0; j < 4; ++j) {
            int rl = mm * 16 + rr + j;           // 0..31
            int col = n * 16 + cc;               // 0..63
            int chunk = (col >> 2) ^ (rl & 15);  // 16 chunks/row
            *(float*)(wb + rl * 256 + chunk * 16 + ((col * 4) & 15)) =
                acc[m][n][j] * (1.0f / 2048.0f);
          }
      }
      __syncthreads();                           // write->read ordering
#pragma unroll
      for (int s = 0; s < 8; ++s) {
        int rl = (lane >> 4) + s * 4;            // 0..31
        int chunk = (lane & 15) ^ (rl & 15);
        f32x4 v = *(const f32x4*)(wb + rl * 256 + chunk * 16);
        *(f32x4*)(&C[(long long)(grow + h * 32 + rl) * Ndim + gcol + (lane & 15) * 4]) = v;
      }
    }
  }
}

// ---------- launch ----------
// ws layout (bytes):
//   S      @ 0          : 16*2048*2048*2 = 134217728
//   zM     @ 134217728  : 16*2048*512*2  =  33554432
//   zH/eT  @ 167772160  :                  33554432   (z fp16; reused as eT)
//   eH     @ 201326592  :                  33554432
//   Mt     @ 234881024  :                    524288
//   colsum @ 235405312  : 16*2048*4      =    131072
extern "C" void kernel_launch(void* const* d_in, const int* in_sizes, int n_in,
                              void* d_out, int out_size, void* d_ws, size_t ws_size,
                              hipStream_t stream) {
  const float* z = (const float*)d_in[0];
  const float* e = (const float*)d_in[1];
  const float* M = (const float*)d_in[2];
  float* out = (float*)d_out;
  char* ws = (char*)d_ws;

  u16* S    = (u16*)(ws + 0LL);
  u16* zM   = (u16*)(ws + 134217728LL);
  u16* zH   = (u16*)(ws + 167772160LL);
  u16* eH   = (u16*)(ws + 201326592LL);
  u16* Mt   = (u16*)(ws + 234881024LL);
  float* cs = (float*)(ws + 235405312LL);

  hipMemsetAsync(cs, 0, (size_t)BB * NE * sizeof(float), stream);

  k_cvt<<<4096, 256, 0, stream>>>(z, zH, BB * NZ * DD / 4);
  k_cvt<<<4096, 256, 0, stream>>>(e, eH, BB * NE * DD / 4);
  k_mt<<<dim3(16, 16), dim3(32, 8), 0, stream>>>(M, Mt);

  // zM[32768 x 512] = zH @ Mt^T   (batch folded into rows); 1024 blocks
  k_gemm<0, 512><<<dim3(DD / 128, (BB * NZ) / 128, 1), 256, 32768, stream>>>(
      zH, Mt, zM, DD, 0LL, 0LL, 0LL, nullptr, 0);

  // S[b] = exp(sigmoid(zM[b] @ eH[b]^T)) ; colsum atomics; 4096 blocks
  k_gemm<1, 512><<<dim3(NE / 128, NZ / 128, BB), 256, 32768, stream>>>(
      zM, eH, S, NE,
      (long long)NZ * DD, (long long)NE * DD, (long long)NZ * NE, cs, NE);

  // eT'[b][d][m] = fp16(eH[b][m][d] * 2048 / colsum[b][m])   (reuses zH region)
  u16* eT = zH;
  k_et<<<dim3(DD / 32, NE / 32, BB), dim3(32, 8), 0, stream>>>(eH, cs, eT);

  // out[b] = (S[b] @ eT[b]^T) / 2048 ; 1024 blocks
  k_gemm<2, 2048><<<dim3(DD / 128, NZ / 128, BB), 256, 32768, stream>>>(
      S, eT, out, DD,
      (long long)NZ * NE, (long long)DD * NE, (long long)NZ * DD, nullptr, 0);
}

// Round 11
// 272.890 us; speedup vs baseline: 1.1180x; 1.1180x over previous
//
#include <hip/hip_runtime.h>
#include <hip/hip_bf16.h>
#include <stdint.h>

#define BB 16
#define NZ 2048
#define NE 2048
#define DD 512

typedef unsigned short u16;
typedef __attribute__((ext_vector_type(8))) _Float16 f16x8;  // 8 fp16 = 4 VGPR
typedef __attribute__((ext_vector_type(4))) float f32x4;

// ---------- helpers ----------
__device__ __forceinline__ u16 f2h(float f) {
  _Float16 h = (_Float16)f;                 // v_cvt_f16_f32, RNE
  return __builtin_bit_cast(u16, h);
}

__device__ __forceinline__ float h2f(u16 h) {
  return (float)__builtin_bit_cast(_Float16, h);
}

__device__ __forceinline__ void gload_lds16(const void* g, void* l) {
  auto gp = (const __attribute__((address_space(1))) uint32_t*)g;
  auto lp = (__attribute__((address_space(3))) uint32_t*)l;
  __builtin_amdgcn_global_load_lds(gp, lp, 16, 0, 0);
}

#define FENCE() asm volatile("" ::: "memory")
#define BARRIER() do { FENCE(); __builtin_amdgcn_s_barrier(); FENCE(); } while (0)
#define WAIT_VM(n) asm volatile("s_waitcnt vmcnt(" #n ")" ::: "memory")

// ---------- f32 -> fp16 bulk convert ----------
__global__ void k_cvt(const float* __restrict__ in, u16* __restrict__ out, int n4) {
  int i = blockIdx.x * blockDim.x + threadIdx.x;
  int stride = gridDim.x * blockDim.x;
  for (; i < n4; i += stride) {
    float4 v = ((const float4*)in)[i];
    ushort4 o;
    o.x = f2h(v.x); o.y = f2h(v.y); o.z = f2h(v.z); o.w = f2h(v.w);
    ((ushort4*)out)[i] = o;
  }
}

// ---------- M[512x512] -> Mt fp16 (Mt[e][d] = M[d][e]) ----------
__global__ void k_mt(const float* __restrict__ M, u16* __restrict__ Mt) {
  __shared__ float t[32][33];
  int bx = blockIdx.x * 32;  // e range
  int by = blockIdx.y * 32;  // d range
  for (int r = 0; r < 32; r += 8)
    t[threadIdx.y + r][threadIdx.x] = M[(size_t)(by + threadIdx.y + r) * DD + bx + threadIdx.x];
  __syncthreads();
  for (int r = 0; r < 32; r += 8)
    Mt[(size_t)(bx + threadIdx.y + r) * DD + by + threadIdx.x] = f2h(t[threadIdx.x][threadIdx.y + r]);
}

// ---------- eT'[b][d][m] = fp16( eH[b][m][d] * 2048 / colsum[b][m] ) ----------
__global__ void k_et(const u16* __restrict__ eH, const float* __restrict__ cs,
                     u16* __restrict__ eT) {
  __shared__ float t[32][33];
  int b = blockIdx.z;
  int m0 = blockIdx.y * 32, d0 = blockIdx.x * 32;
  const u16* eb = eH + (size_t)b * NE * DD;
  const float* csb = cs + (size_t)b * NE;
  for (int r = 0; r < 32; r += 8) {
    int m = m0 + threadIdx.y + r;
    t[threadIdx.y + r][threadIdx.x] =
        h2f(eb[(size_t)m * DD + d0 + threadIdx.x]) * (2048.0f / csb[m]);
  }
  __syncthreads();
  u16* eTb = eT + (size_t)b * DD * NE;
  for (int r = 0; r < 32; r += 8) {
    int d = d0 + threadIdx.y + r;
    eTb[(size_t)d * NE + m0 + threadIdx.x] = f2h(t[threadIdx.x][threadIdx.y + r]);
  }
}

// ---------- 256x256 tile, BK=32, 8-wave fp16 gemm_bt, 4-slot LDS ring ----------
// C = A[M x K] * Bt[N x K]^T.  512 threads = 8 waves (2M x 4N), per-wave
// 128x64 = 8m x 4n fragments -> 12 ds_read_b128 per 32 MFMA (0.375 ratio).
// LDS 128 KiB = 4 ring slots x 32 KiB (A 16K @ +0, B 16K @ +16384).
// Linear 64-B rows with XOR chunk swizzle (r10-verified: coalesced staging +
// 0 bank conflicts): slot (r,cL) holds source chunk q = cL ^ ((r>>1)&3).
// Schedule per K-step t (ONE barrier):
//   stage(t+2) -> ring[(t+2)&3]   (>= 2 slots from any reader: race-free)
//   WAIT_VM(8) steady / (4) at t=NT-2 / (0) at t=NT-1  -> tile t landed
//   BARRIER; read A(8)+B(2); setprio1; 16 MFMA; setprio0; read B(2); 16 MFMA
// ~2 K-steps of prefetch lead (>600 cyc) covers HBM/L2 latency; vmcnt never 0
// in steady state.  Epilogue: r9's LDS-staged coalesced writeback.
// EPI: 0 = fp16 out; 1 = exp(sigmoid(x)) fp16 out + colsum atomics; 2 = f32/2048
template<int EPI, int KDIM>
__global__ __launch_bounds__(512, 2) void k_gemm(
    const u16* __restrict__ A, const u16* __restrict__ Bt, void* __restrict__ Cp,
    int Ndim, long long sAb, long long sBb, long long sCb,
    float* __restrict__ colsum, int csld)
{
  extern __shared__ char lds[];
  constexpr int NT = KDIM / 32;

  // bijective XCD-aware swizzle (nwg % 8 == 0 for all our launches)
  const int gx = gridDim.x, gy = gridDim.y;
  const int nwg = gx * gy * gridDim.z;
  const int hid = blockIdx.x + gx * (blockIdx.y + gy * blockIdx.z);
  const int logical = (hid & 7) * (nwg >> 3) + (hid >> 3);
  const int bx = logical % gx;
  const int rem0 = logical / gx;
  const int by = rem0 % gy;
  const int bz = rem0 / gy;

  const int tid = threadIdx.x;
  const int lane = tid & 63;
  const int wid = tid >> 6;
  const int wr = wid >> 2;   // 0..1
  const int wc = wid & 3;    // 0..3

  const int row0 = by * 256;
  const int col0 = bx * 256;

  const u16* Ab = A + (long long)bz * sAb;
  const u16* Bb = Bt + (long long)bz * sBb;

  // staging sources: instr c covers LDS slots idx = c*512 + tid;
  // r = idx>>2 (0..255), cL = idx&3; source chunk q = cL ^ ((r>>1)&3)
  const u16* srcA[2]; const u16* srcB[2];
#pragma unroll
  for (int c = 0; c < 2; ++c) {
    int idx = c * 512 + tid;
    int r = idx >> 2;
    int cL = idx & 3;
    int q = cL ^ ((r >> 1) & 3);
    srcA[c] = Ab + (long long)(row0 + r) * KDIM + q * 8;
    srcB[c] = Bb + (long long)(col0 + r) * KDIM + q * 8;
  }

  auto stage = [&](int t) {
    const int k0 = t * 32;
    char* d = lds + (t & 3) * 32768;
#pragma unroll
    for (int c = 0; c < 2; ++c)
      gload_lds16(srcA[c] + k0, d + (c * 512 + wid * 64) * 16);
#pragma unroll
    for (int c = 0; c < 2; ++c)
      gload_lds16(srcB[c] + k0, d + 16384 + (c * 512 + wid * 64) * 16);
  };

  const int p15 = lane & 15;
  const int hi = lane >> 4;

  auto ldA = [&](int t, int m) -> f16x8 {
    int r = wr * 128 + m * 16 + p15;
    int c4 = hi ^ ((r >> 1) & 3);
    return *(const f16x8*)(lds + (t & 3) * 32768 + r * 64 + c4 * 16);
  };
  auto ldB = [&](int t, int n) -> f16x8 {
    int r = wc * 64 + n * 16 + p15;
    int c4 = hi ^ ((r >> 1) & 3);
    return *(const f16x8*)(lds + (t & 3) * 32768 + 16384 + r * 64 + c4 * 16);
  };

  f32x4 acc[8][4] = {};

  stage(0);
  stage(1);

  for (int t = 0; t < NT; ++t) {
    if (t + 2 < NT) { stage(t + 2); WAIT_VM(8); }
    else if (t + 1 < NT) { WAIT_VM(4); }
    else { WAIT_VM(0); }
    BARRIER();

    f16x8 af[8], bf[2];
#pragma unroll
    for (int m = 0; m < 8; ++m) af[m] = ldA(t, m);

    // phase 0: n = 0,1
    bf[0] = ldB(t, 0); bf[1] = ldB(t, 1);
    __builtin_amdgcn_s_setprio(1);
#pragma unroll
    for (int m = 0; m < 8; ++m) {
      acc[m][0] = __builtin_amdgcn_mfma_f32_16x16x32_f16(af[m], bf[0], acc[m][0], 0, 0, 0);
      acc[m][1] = __builtin_amdgcn_mfma_f32_16x16x32_f16(af[m], bf[1], acc[m][1], 0, 0, 0);
    }
    __builtin_amdgcn_s_setprio(0);

    // phase 1: n = 2,3
    bf[0] = ldB(t, 2); bf[1] = ldB(t, 3);
    __builtin_amdgcn_s_setprio(1);
#pragma unroll
    for (int m = 0; m < 8; ++m) {
      acc[m][2] = __builtin_amdgcn_mfma_f32_16x16x32_f16(af[m], bf[0], acc[m][2], 0, 0, 0);
      acc[m][3] = __builtin_amdgcn_mfma_f32_16x16x32_f16(af[m], bf[1], acc[m][3], 0, 0, 0);
    }
    __builtin_amdgcn_s_setprio(0);
  }

  __syncthreads();   // all reads done; LDS free for epilogue reuse

  // C/D frag layout: col = lane&15, row = (lane>>4)*4 + j
  const int rr = (lane >> 4) * 4;
  const int cc = lane & 15;
  const int grow = row0 + wr * 128;
  const int gcol = col0 + wc * 64;

  if constexpr (EPI == 0 || EPI == 1) {
    // stage u16 128x64 wave-tile in LDS (16 KiB/wave), coalesced dwordx4 out
    char* wb = lds + wid * 16384;
    float csum[4] = {0.f, 0.f, 0.f, 0.f};
#pragma unroll
    for (int m = 0; m < 8; ++m)
#pragma unroll
      for (int n = 0; n < 4; ++n)
#pragma unroll
        for (int j = 0; j < 4; ++j) {
          float x = acc[m][n][j];
          float v;
          if constexpr (EPI == 1) {
            float s = 1.f / (1.f + __expf(-x));   // sigmoid
            v = __expf(s);                        // in (1, e)
            csum[n] += v;
          } else {
            v = x;
          }
          int rl = m * 16 + rr + j;              // 0..127
          int col = n * 16 + cc;                 // 0..63
          int chunk = (col >> 3) ^ (rl & 7);     // bank swizzle
          *(u16*)(wb + rl * 128 + chunk * 16 + ((col * 2) & 15)) = f2h(v);
        }
    if constexpr (EPI == 1) {
#pragma unroll
      for (int n = 0; n < 4; ++n) {
        float v = csum[n];
        v += __shfl_xor(v, 16, 64);
        v += __shfl_xor(v, 32, 64);
        if ((lane >> 4) == 0)
          atomicAdd(&colsum[(long long)bz * csld + gcol + n * 16 + cc], v);
      }
    }
    __syncthreads();   // cross-lane LDS write->read ordering (r6 fix)
    u16* C = (u16*)Cp + (long long)bz * sCb;
#pragma unroll
    for (int s = 0; s < 16; ++s) {
      int rl = (lane >> 3) + s * 8;              // 0..127
      int chunk = (lane & 7) ^ (rl & 7);
      f16x8 v = *(const f16x8*)(wb + rl * 128 + chunk * 16);
      *(f16x8*)(&C[(long long)(grow + rl) * Ndim + gcol + (lane & 7) * 8]) = v;
    }
  } else {
    // f32 out: two 64-row passes, 16 KiB/wave each, coalesced dwordx4
    float* C = (float*)Cp + (long long)bz * sCb;
    char* wb = lds + wid * 16384;
#pragma unroll
    for (int h = 0; h < 2; ++h) {
      if (h) __syncthreads();                    // pass-0 reads done before overwrite
#pragma unroll
      for (int mm = 0; mm < 4; ++mm) {
        int m = h * 4 + mm;
#pragma unroll
        for (int n = 0; n < 4; ++n)
#pragma unroll
          for (int j = 0; j < 4; ++j) {
            int rl = mm * 16 + rr + j;           // 0..63
            int col = n * 16 + cc;               // 0..63
            int chunk = (col >> 2) ^ (rl & 15);  // 16 chunks/row
            *(float*)(wb + rl * 256 + chunk * 16 + ((col * 4) & 15)) =
                acc[m][n][j] * (1.0f / 2048.0f);
          }
      }
      __syncthreads();                           // write->read ordering
#pragma unroll
      for (int s = 0; s < 16; ++s) {
        int rl = (lane >> 4) + s * 4;            // 0..63
        int chunk = (lane & 15) ^ (rl & 15);
        f32x4 v = *(const f32x4*)(wb + rl * 256 + chunk * 16);
        *(f32x4*)(&C[(long long)(grow + h * 64 + rl) * Ndim + gcol + (lane & 15) * 4]) = v;
      }
    }
  }
}

// ---------- launch ----------
// ws layout (bytes):
//   S      @ 0          : 16*2048*2048*2 = 134217728
//   zM     @ 134217728  : 16*2048*512*2  =  33554432
//   zH/eT  @ 167772160  :                  33554432   (z fp16; reused as eT)
//   eH     @ 201326592  :                  33554432
//   Mt     @ 234881024  :                    524288
//   colsum @ 235405312  : 16*2048*4      =    131072
extern "C" void kernel_launch(void* const* d_in, const int* in_sizes, int n_in,
                              void* d_out, int out_size, void* d_ws, size_t ws_size,
                              hipStream_t stream) {
  const float* z = (const float*)d_in[0];
  const float* e = (const float*)d_in[1];
  const float* M = (const float*)d_in[2];
  float* out = (float*)d_out;
  char* ws = (char*)d_ws;

  u16* S    = (u16*)(ws + 0LL);
  u16* zM   = (u16*)(ws + 134217728LL);
  u16* zH   = (u16*)(ws + 167772160LL);
  u16* eH   = (u16*)(ws + 201326592LL);
  u16* Mt   = (u16*)(ws + 234881024LL);
  float* cs = (float*)(ws + 235405312LL);

  (void)hipFuncSetAttribute(reinterpret_cast<const void*>(&k_gemm<0, 512>),
                            hipFuncAttributeMaxDynamicSharedMemorySize, 131072);
  (void)hipFuncSetAttribute(reinterpret_cast<const void*>(&k_gemm<1, 512>),
                            hipFuncAttributeMaxDynamicSharedMemorySize, 131072);
  (void)hipFuncSetAttribute(reinterpret_cast<const void*>(&k_gemm<2, 2048>),
                            hipFuncAttributeMaxDynamicSharedMemorySize, 131072);

  hipMemsetAsync(cs, 0, (size_t)BB * NE * sizeof(float), stream);

  k_cvt<<<4096, 256, 0, stream>>>(z, zH, BB * NZ * DD / 4);
  k_cvt<<<4096, 256, 0, stream>>>(e, eH, BB * NE * DD / 4);
  k_mt<<<dim3(16, 16), dim3(32, 8), 0, stream>>>(M, Mt);

  // zM[32768 x 512] = zH @ Mt^T   (batch folded into rows); 256 blocks
  k_gemm<0, 512><<<dim3(DD / 256, (BB * NZ) / 256, 1), 512, 131072, stream>>>(
      zH, Mt, zM, DD, 0LL, 0LL, 0LL, nullptr, 0);

  // S[b] = exp(sigmoid(zM[b] @ eH[b]^T)) ; colsum atomics; 1024 blocks
  k_gemm<1, 512><<<dim3(NE / 256, NZ / 256, BB), 512, 131072, stream>>>(
      zM, eH, S, NE,
      (long long)NZ * DD, (long long)NE * DD, (long long)NZ * NE, cs, NE);

  // eT'[b][d][m] = fp16(eH[b][m][d] * 2048 / colsum[b][m])   (reuses zH region)
  u16* eT = zH;
  k_et<<<dim3(DD / 32, NE / 32, BB), dim3(32, 8), 0, stream>>>(eH, cs, eT);

  // out[b] = (S[b] @ eT[b]^T) / 2048 ; 256 blocks
  k_gemm<2, 2048><<<dim3(DD / 256, NZ / 256, BB), 512, 131072, stream>>>(
      S, eT, out, DD,
      (long long)NZ * NE, (long long)DD * NE, (long long)NZ * DD, nullptr, 0);
}